// Round 13
// baseline (219.533 us; speedup 1.0000x reference)
//
#include <hip/hip_runtime.h>

// ---------------------------------------------------------------------------
// LIIF forward, MI355X — ROUND 13 = PHASE-ABLATION DIAGNOSTIC.
// Real pipeline = r7 verbatim (44.4 us, passing): k_prepw, k_stage1, k_stage2.
// Added: three stripped stage2 phase-clones (scratch output, REPS-looped so
// they surface in rocprof top-5 with counters):
//   s2_diagA: A-frag load stream only (XOR-consumed)        REPS=8
//   s2_diagB: MFMA+pack+permlane chain only (no loads)      REPS=16
//   s2_diagC: h0 prologue only (gather + w0-tail + pack)    REPS=8
// Diags write to ws scratch past all live data; real k_stage2 runs last and
// produces d_out. Next round reverts to 3 kernels + applies the finding.
// ---------------------------------------------------------------------------

typedef unsigned short U16;
typedef unsigned int   u32;
using f16x8  = __attribute__((ext_vector_type(8)))  _Float16;
using f32x4  = __attribute__((ext_vector_type(4)))  float;
using f32x16 = __attribute__((ext_vector_type(16))) float;
using u16x8  = __attribute__((ext_vector_type(8)))  U16;
using u16x4  = __attribute__((ext_vector_type(4)))  U16;

// ws layout (f16 element offsets)
#define P_OFF    2097152    // 2*16384*128  = 4,194,304
#define W0F_OFF  6291456    // 73,728  stage1 A-frags
#define W1F_OFF  6365184    // 3*16384 stage2 A-frags: [L][s][mt][lane][8]
#define W4F_OFF  6414336    // 8,192   stage2 final:   [s][mt4][lane][8]
#define DIAG_OFF 6422528    // diag scratch (u32 stores), 3 x 512 KB

__device__ __forceinline__ float h2f(U16 u){ _Float16 h; __builtin_memcpy(&h,&u,2); return (float)h; }
__device__ __forceinline__ U16 f2h(float f){ _Float16 h = (_Float16)f; U16 u; __builtin_memcpy(&u,&h,2); return u; }
__device__ __forceinline__ u32 packf16(float a, float b){
  _Float16 ha = (_Float16)a, hb = (_Float16)b;
  U16 ua, ub; __builtin_memcpy(&ua,&ha,2); __builtin_memcpy(&ub,&hb,2);
  return (u32)ua | ((u32)ub << 16);
}
__device__ __forceinline__ f16x8 bfrag(const u32* w){
  union { u32 u[4]; f16x8 v; } t;
  t.u[0]=w[0]; t.u[1]=w[1]; t.u[2]=w[2]; t.u[3]=w[3];
  return t.v;
}
__device__ __forceinline__ u32 xor8(f16x8 v){
  union { f16x8 f; u32 u[4]; } t; t.f = v;
  return t.u[0] ^ t.u[1] ^ t.u[2] ^ t.u[3];
}

__device__ __forceinline__ int nearest_idx(float g){
  float t = (g + 1.0f) * 128.0f;
  t = (t - 1.0f) * 0.5f;
  float r = rintf(t);
  r = fminf(fmaxf(r, 0.0f), 127.0f);
  return (int)r;
}
__device__ __forceinline__ float seqv(int i){ return -0.9921875f + 0.015625f*(float)i; }

__device__ __forceinline__ void corner_calc(float c0, float c1, int corner,
                                            int& iy, int& ix, float& rel0, float& rel1){
  const float rx = 0.0078125f;
  float sx = (corner & 2) ? rx : -rx;
  float sy = (corner & 1) ? rx : -rx;
  float a0 = c0 + sx; a0 = a0 + 1e-6f; a0 = fminf(fmaxf(a0, -1.0f + 1e-6f), 1.0f - 1e-6f);
  float a1 = c1 + sy; a1 = a1 + 1e-6f; a1 = fminf(fmaxf(a1, -1.0f + 1e-6f), 1.0f - 1e-6f);
  iy = nearest_idx(a0);
  ix = nearest_idx(a1);
  rel0 = (c0 - seqv(ix)) * 128.0f;
  rel1 = (c1 - seqv(iy)) * 128.0f;
}

// ---------------------------------------------------------------------------
// k_prepw: 50 blocks (verbatim r7).
__global__ __launch_bounds__(256) void k_prepw(
    const float* __restrict__ w0, const float* __restrict__ w1,
    const float* __restrict__ w2, const float* __restrict__ w3,
    const float* __restrict__ w4, U16* __restrict__ ws)
{
  __shared__ U16 sh[64 * 72];
  const int tid = threadIdx.x, bid = blockIdx.x;

  if (bid < 24) {
    int L = bid >> 3, s = bid & 7;
    const float* src = (L == 0) ? w1 : (L == 1) ? w2 : w3;
    {
      int kk = tid >> 4, m0 = (tid & 15) << 3;
      const float* p = src + (((s << 4) + kk) << 7) + m0;
      float4 a = *(const float4*)p, b2v = *(const float4*)(p + 4);
      U16* d = &sh[kk * 128 + m0];
      d[0]=f2h(a.x); d[1]=f2h(a.y); d[2]=f2h(a.z); d[3]=f2h(a.w);
      d[4]=f2h(b2v.x); d[5]=f2h(b2v.y); d[6]=f2h(b2v.z); d[7]=f2h(b2v.w);
    }
    __syncthreads();
    {
      int mt = tid >> 6, lane = tid & 63;
      u16x8 o;
      #pragma unroll
      for (int e = 0; e < 8; ++e)
        o[e] = sh[((((lane >> 5) << 3) + e) << 7) + (mt << 5) + (lane & 31)];
      *(u16x8*)(ws + W1F_OFF + (L << 14) + (((s << 2) + mt) << 9) + (lane << 3)) = o;
    }
  } else if (bid < 32) {
    int s = bid - 24;
    {
      int kk = tid >> 4, m0 = (tid & 15) << 2;
      float4 a = *(const float4*)(w4 + (((s << 4) + kk) << 6) + m0);
      U16* d = &sh[kk * 64 + m0];
      d[0]=f2h(a.x); d[1]=f2h(a.y); d[2]=f2h(a.z); d[3]=f2h(a.w);
    }
    __syncthreads();
    if (tid < 128) {
      int mt4 = tid >> 6, lane = tid & 63;
      u16x8 o;
      #pragma unroll
      for (int e = 0; e < 8; ++e)
        o[e] = sh[((((lane >> 5) << 3) + e) << 6) + (mt4 << 5) + (lane & 31)];
      *(u16x8*)(ws + W4F_OFF + (((s << 1) + mt4) << 9) + (lane << 3)) = o;
    }
  } else {
    int t2 = bid - 32, kpos = t2 >> 1, ks = t2 & 1;
    {
      int cc = tid >> 3, o0 = (tid & 7) << 4;
      const float* p = w0 + ((size_t)((((ks << 5) + cc) * 9) + kpos) << 7) + o0;
      #pragma unroll
      for (int j = 0; j < 4; ++j) {
        float4 v = *(const float4*)(p + (j << 2));
        U16* d = &sh[(cc << 7) + o0 + (j << 2)];
        d[0]=f2h(v.x); d[1]=f2h(v.y); d[2]=f2h(v.z); d[3]=f2h(v.w);
      }
    }
    __syncthreads();
    {
      int lane = tid & 63, mt0 = tid >> 6;
      #pragma unroll
      for (int i = 0; i < 2; ++i) {
        int mtile = mt0 + (i << 2);
        u16x8 o;
        #pragma unroll
        for (int e = 0; e < 8; ++e)
          o[e] = sh[((((lane >> 4) << 3) + e) << 7) + (mtile << 4) + (lane & 15)];
        *(u16x8*)(ws + W0F_OFF + (((((kpos << 1) + ks) << 3) + mtile) << 9) + (lane << 3)) = o;
      }
    }
  }
}

// ---------------------------------------------------------------------------
// Stage 1 (fused transpose+conv): verbatim r7.
__global__ __launch_bounds__(256) void k_stage1(const float* __restrict__ x,
                                                const U16* __restrict__ w0f,
                                                const float* __restrict__ b0,
                                                U16* __restrict__ P)
{
  __shared__ U16 araw[3 * 66 * 64];
  const int tid = threadIdx.x, bid = blockIdx.x;
  const int b = bid >> 8, rem = bid & 255;
  const int y = rem >> 1, x0 = (rem & 1) << 6;

  {
    int c = tid & 63, dy = tid >> 6;
    if (dy < 3) {
      int yy = y + dy - 1;
      bool rowok = (yy >= 0) && (yy < 128);
      const float* xr = rowok
        ? (x + ((((size_t)b << 6) + c) << 14) + ((size_t)yy << 7)) : x;
      U16* arow = &araw[(dy * 66) * 64];
      {
        float v0 = 0.0f, v65 = 0.0f;
        if (rowok && x0 > 0)        v0  = xr[x0 - 1];
        if (rowok && x0 + 64 < 128) v65 = xr[x0 + 64];
        arow[0 * 64 + c] = f2h(v0);
        arow[65 * 64 + (c ^ 8)] = f2h(v65);
      }
      if (rowok) {
        #pragma unroll
        for (int g = 0; g < 16; ++g) {
          float4 v = *(const float4*)(xr + x0 + (g << 2));
          #pragma unroll
          for (int j = 0; j < 4; ++j) {
            int xp = 1 + (g << 2) + j;
            float vj = (j == 0) ? v.x : (j == 1) ? v.y : (j == 2) ? v.z : v.w;
            arow[xp * 64 + (c ^ ((xp & 7) << 3))] = f2h(vj);
          }
        }
      } else {
        #pragma unroll
        for (int xp = 1; xp <= 64; ++xp)
          arow[xp * 64 + (c ^ ((xp & 7) << 3))] = f2h(0.0f);
      }
    }
  }
  __syncthreads();

  const int wv = tid >> 6, ln = tid & 63;
  const int lrow = ln & 15, lg = ln >> 4;

  f32x4 acc[2][4];
  #pragma unroll
  for (int m = 0; m < 2; ++m)
    #pragma unroll
    for (int n = 0; n < 4; ++n) acc[m][n] = (f32x4){0.f, 0.f, 0.f, 0.f};

  #pragma unroll
  for (int kpos = 0; kpos < 9; ++kpos) {
    const int dyr = kpos / 3;
    const int dx = kpos % 3 - 1;
    f16x8 a[2][2];
    #pragma unroll
    for (int mf = 0; mf < 2; ++mf)
      #pragma unroll
      for (int ks = 0; ks < 2; ++ks) {
        size_t off = ((size_t)((((kpos << 1) + ks) << 3) + ((wv << 1) + mf)) << 9) + (ln << 3);
        a[mf][ks] = *(const f16x8*)(w0f + off);
      }
    #pragma unroll
    for (int ks = 0; ks < 2; ++ks)
      #pragma unroll
      for (int nf = 0; nf < 4; ++nf) {
        int xp = (nf << 4) + lrow + dx + 1;
        int cc = ((ks << 5) + (lg << 3)) ^ ((xp & 7) << 3);
        f16x8 bf = *(const f16x8*)(&araw[(dyr * 66 + xp) * 64 + cc]);
        acc[0][nf] = __builtin_amdgcn_mfma_f32_16x16x32_f16(a[0][ks], bf, acc[0][nf], 0, 0, 0);
        acc[1][nf] = __builtin_amdgcn_mfma_f32_16x16x32_f16(a[1][ks], bf, acc[1][nf], 0, 0, 0);
      }
  }

  #pragma unroll
  for (int mf = 0; mf < 2; ++mf) {
    int o0 = (wv << 5) + (mf << 4) + (lg << 2);
    float bb[4];
    #pragma unroll
    for (int r = 0; r < 4; ++r) bb[r] = b0[o0 + r];
    #pragma unroll
    for (int nf = 0; nf < 4; ++nf) {
      int px = x0 + (nf << 4) + lrow;
      u16x4 w;
      #pragma unroll
      for (int r = 0; r < 4; ++r) w[r] = f2h(acc[mf][nf][r] + bb[r]);
      *(u16x4*)(P + ((size_t)((b << 14) + (y << 7) + px)) * 128 + o0) = w;
    }
  }
}

// ---------------------------------------------------------------------------
// s2_diagA: the A-frag load stream alone (112 loads/wave), XOR-consumed.
__global__ __launch_bounds__(256) void s2_diagA(
    const U16* __restrict__ w1f, const U16* __restrict__ w2f,
    const U16* __restrict__ w3f, const U16* __restrict__ w4f,
    u32* __restrict__ dout)
{
  const int tid = threadIdx.x;
  const int ln = tid & 63, lnoff = ln << 3;
  u32 acc = 0;
  for (int rep = 0; rep < 8; ++rep) {
    asm volatile("" ::: "memory");
    const U16* wf_[3] = {w1f, w2f, w3f};
    #pragma unroll
    for (int L = 0; L < 3; ++L) {
      const U16* wf = wf_[L];
      #pragma unroll
      for (int s = 0; s < 8; ++s)
        #pragma unroll
        for (int mt = 0; mt < 4; ++mt)
          acc ^= xor8(*(const f16x8*)(wf + (((s << 2) + mt) << 9) + lnoff));
    }
    #pragma unroll
    for (int s = 0; s < 8; ++s)
      #pragma unroll
      for (int mt4 = 0; mt4 < 2; ++mt4)
        acc ^= xor8(*(const f16x8*)(w4f + (((s << 1) + mt4) << 9) + lnoff));
  }
  dout[blockIdx.x * 256 + tid] = acc;
}

// ---------------------------------------------------------------------------
// s2_diagB: MFMA + pack + permlane dependency chain only (no memory).
__global__ __launch_bounds__(256) void s2_diagB(u32* __restrict__ dout)
{
  const int tid = threadIdx.x;
  const int ln = tid & 63;
  u32 sink = 0;
  u32 Bf[8][4];
  f16x8 Ac[4];
  #pragma unroll
  for (int s = 0; s < 8; ++s)
    #pragma unroll
    for (int w = 0; w < 4; ++w)
      Bf[s][w] = packf16(0.01f * (float)((ln + s) & 7), 0.015f * (float)(w + 1));
  #pragma unroll
  for (int mt = 0; mt < 4; ++mt) {
    union { u32 u[4]; f16x8 v; } t;
    #pragma unroll
    for (int w = 0; w < 4; ++w)
      t.u[w] = packf16(0.02f * (float)((ln + mt + w) & 7), 0.01f);
    Ac[mt] = t.v;
  }
  for (int rep = 0; rep < 16; ++rep) {
    asm volatile("" ::: "memory");
    #pragma unroll
    for (int L = 0; L < 3; ++L) {
      f32x16 acc[4];
      #pragma unroll
      for (int mt = 0; mt < 4; ++mt)
        #pragma unroll
        for (int r = 0; r < 16; ++r) acc[mt][r] = 0.0f;
      #pragma unroll
      for (int s = 0; s < 8; ++s) {
        f16x8 B = bfrag(Bf[s]);
        #pragma unroll
        for (int mt = 0; mt < 4; ++mt)
          acc[mt] = __builtin_amdgcn_mfma_f32_32x32x16_f16(Ac[mt], B, acc[mt], 0, 0, 0);
      }
      #pragma unroll
      for (int mtp = 0; mtp < 4; ++mtp) {
        u32 p[8];
        #pragma unroll
        for (int j2 = 0; j2 < 8; ++j2)
          p[j2] = packf16(fmaxf(acc[mtp][2 * j2], 0.0f), fmaxf(acc[mtp][2 * j2 + 1], 0.0f));
        #pragma unroll
        for (int u = 0; u < 2; ++u)
          #pragma unroll
          for (int w = 0; w < 2; ++w) {
            u32 va = p[w + 4 * u], vb = p[w + 4 * u + 2];
            asm("v_permlane32_swap_b32 %0, %1" : "+v"(va), "+v"(vb));
            Bf[2 * mtp + u][w]     = va;
            Bf[2 * mtp + u][w + 2] = vb;
          }
      }
    }
    f32x16 a4[2];
    #pragma unroll
    for (int mt4 = 0; mt4 < 2; ++mt4)
      #pragma unroll
      for (int r = 0; r < 16; ++r) a4[mt4][r] = 0.0f;
    #pragma unroll
    for (int s = 0; s < 8; ++s) {
      f16x8 B = bfrag(Bf[s]);
      #pragma unroll
      for (int mt4 = 0; mt4 < 2; ++mt4)
        a4[mt4] = __builtin_amdgcn_mfma_f32_32x32x16_f16(Ac[mt4], B, a4[mt4], 0, 0, 0);
    }
    #pragma unroll
    for (int mt4 = 0; mt4 < 2; ++mt4)
      #pragma unroll
      for (int r = 0; r < 16; ++r)
        sink ^= (u32)__float_as_uint(a4[mt4][r]);
  }
  dout[blockIdx.x * 256 + tid] = sink;
}

// ---------------------------------------------------------------------------
// s2_diagC: h0 prologue only (corner math + P gather + w0-tail + pack).
__global__ __launch_bounds__(256) void s2_diagC(
    const U16* __restrict__ P,
    const float* __restrict__ coord, const float* __restrict__ cell,
    const float* __restrict__ w0, u32* __restrict__ dout)
{
  const int tid = threadIdx.x;
  const int wv = tid >> 6, ln = tid & 63;
  const int wave = blockIdx.x * 4 + wv;
  const int q0 = wave << 3;
  const int col = ln & 31, h = ln >> 5;
  const int qi = col >> 2, c = col & 3;
  const int gq = q0 + qi;
  const int bimg = gq >> 13;
  u32 sink = 0;

  for (int rep = 0; rep < 8; ++rep) {
    asm volatile("" ::: "memory");
    float c0v = coord[gq * 2 + 0], c1v = coord[gq * 2 + 1];
    float rc0 = cell[gq * 2 + 0] * 128.0f, rc1 = cell[gq * 2 + 1] * 128.0f;
    int lin4[4]; float r0v[4], r1v[4];
    #pragma unroll
    for (int c4 = 0; c4 < 4; ++c4) {
      int iy, ix; float r0, r1;
      corner_calc(c0v, c1v, c4, iy, ix, r0, r1);
      lin4[c4] = iy * 128 + ix;
      r0v[c4] = r0; r1v[c4] = r1;
    }
    float rel0 = r0v[c], rel1 = r1v[c];
    const U16* Pr = P + ((size_t)(bimg << 14) + lin4[c]) * 128;
    u16x8 pv[8];
    #pragma unroll
    for (int s = 0; s < 8; ++s)
      pv[s] = *(const u16x8*)(Pr + (s << 4) + (h << 3));
    const float* tu = w0 + 576 * 128;
    const float* tv = tu + 128;
    const float* ts2 = tv + 128;
    const float* tt = ts2 + 128;
    #pragma unroll
    for (int s = 0; s < 8; ++s) {
      int k0 = (s << 4) + (h << 3);
      f32x4 ua = *(const f32x4*)(tu + k0),  ub = *(const f32x4*)(tu + k0 + 4);
      f32x4 va = *(const f32x4*)(tv + k0),  vb = *(const f32x4*)(tv + k0 + 4);
      f32x4 sa = *(const f32x4*)(ts2 + k0), sb = *(const f32x4*)(ts2 + k0 + 4);
      f32x4 ta = *(const f32x4*)(tt + k0),  tb = *(const f32x4*)(tt + k0 + 4);
      float hh[8];
      #pragma unroll
      for (int e = 0; e < 8; ++e) {
        float uu  = (e < 4) ? ua[e & 3] : ub[e & 3];
        float vvv = (e < 4) ? va[e & 3] : vb[e & 3];
        float ss  = (e < 4) ? sa[e & 3] : sb[e & 3];
        float t2  = (e < 4) ? ta[e & 3] : tb[e & 3];
        hh[e] = fmaxf(h2f(pv[s][e]) + rel0 * uu + rel1 * vvv + rc0 * ss + rc1 * t2, 0.0f);
      }
      #pragma unroll
      for (int w = 0; w < 4; ++w)
        sink ^= packf16(hh[2 * w], hh[2 * w + 1]);
    }
  }
  dout[blockIdx.x * 256 + tid] = sink;
}

// ---------------------------------------------------------------------------
// Stage 2: verbatim r7 (passing, produces d_out).
__global__ __launch_bounds__(256) void k_stage2(
    const U16* __restrict__ P,
    const float* __restrict__ coord, const float* __restrict__ cell,
    const float* __restrict__ w0,
    const U16* __restrict__ w1f, const U16* __restrict__ w2f,
    const U16* __restrict__ w3f, const U16* __restrict__ w4f,
    const float* __restrict__ b1, const float* __restrict__ b2,
    const float* __restrict__ b3, const float* __restrict__ b4,
    float* __restrict__ out)
{
  const int tid = threadIdx.x;
  const int wv = tid >> 6, ln = tid & 63;
  const int wave = blockIdx.x * 4 + wv;
  const int q0 = wave << 3;
  const int col = ln & 31, h = ln >> 5;
  const int qi = col >> 2, c = col & 3;
  const int gq = q0 + qi;
  const int bimg = gq >> 13;

  float c0v = coord[gq * 2 + 0], c1v = coord[gq * 2 + 1];
  float rc0 = cell[gq * 2 + 0] * 128.0f, rc1 = cell[gq * 2 + 1] * 128.0f;
  int lin4[4]; float r0v[4], r1v[4], area[4];
  #pragma unroll
  for (int c4 = 0; c4 < 4; ++c4) {
    int iy, ix; float r0, r1;
    corner_calc(c0v, c1v, c4, iy, ix, r0, r1);
    lin4[c4] = iy * 128 + ix;
    r0v[c4] = r0; r1v[c4] = r1;
    area[c4] = fabsf(r0 * r1) + 1e-9f;
  }
  float tot = ((area[0] + area[1]) + area[2]) + area[3];
  float wgt = area[3 - c] / tot;
  float rel0 = r0v[c], rel1 = r1v[c];

  const U16* Pr = P + ((size_t)(bimg << 14) + lin4[c]) * 128;
  u16x8 pv[8];
  #pragma unroll
  for (int s = 0; s < 8; ++s)
    pv[s] = *(const u16x8*)(Pr + (s << 4) + (h << 3));

  u32 Bf[8][4];
  {
    const float* tu = w0 + 576 * 128;
    const float* tv = tu + 128;
    const float* ts2 = tv + 128;
    const float* tt = ts2 + 128;
    #pragma unroll
    for (int s = 0; s < 8; ++s) {
      int k0 = (s << 4) + (h << 3);
      f32x4 ua = *(const f32x4*)(tu + k0),  ub = *(const f32x4*)(tu + k0 + 4);
      f32x4 va = *(const f32x4*)(tv + k0),  vb = *(const f32x4*)(tv + k0 + 4);
      f32x4 sa = *(const f32x4*)(ts2 + k0), sb = *(const f32x4*)(ts2 + k0 + 4);
      f32x4 ta = *(const f32x4*)(tt + k0),  tb = *(const f32x4*)(tt + k0 + 4);
      float hh[8];
      #pragma unroll
      for (int e = 0; e < 8; ++e) {
        float uu  = (e < 4) ? ua[e & 3] : ub[e & 3];
        float vvv = (e < 4) ? va[e & 3] : vb[e & 3];
        float ss  = (e < 4) ? sa[e & 3] : sb[e & 3];
        float t2  = (e < 4) ? ta[e & 3] : tb[e & 3];
        hh[e] = fmaxf(h2f(pv[s][e]) + rel0 * uu + rel1 * vvv + rc0 * ss + rc1 * t2, 0.0f);
      }
      #pragma unroll
      for (int w = 0; w < 4; ++w)
        Bf[s][w] = packf16(hh[2 * w], hh[2 * w + 1]);
    }
  }

  const U16* wf_[3] = {w1f, w2f, w3f};
  const float* bL_[3] = {b1, b2, b3};
  #pragma unroll
  for (int L = 0; L < 3; ++L) {
    const U16* wf = wf_[L];
    const float* bL = bL_[L];
    f32x16 acc[4];
    #pragma unroll
    for (int mt = 0; mt < 4; ++mt)
      #pragma unroll
      for (int j = 0; j < 4; ++j) {
        f32x4 bv = *(const f32x4*)(bL + (mt << 5) + (j << 3) + (h << 2));
        #pragma unroll
        for (int q = 0; q < 4; ++q) acc[mt][4 * j + q] = bv[q];
      }
    #pragma unroll
    for (int s = 0; s < 8; ++s) {
      f16x8 B = bfrag(Bf[s]);
      #pragma unroll
      for (int mt = 0; mt < 4; ++mt) {
        f16x8 A = *(const f16x8*)(wf + (((size_t)(s * 4 + mt) * 64 + ln) << 3));
        acc[mt] = __builtin_amdgcn_mfma_f32_32x32x16_f16(A, B, acc[mt], 0, 0, 0);
      }
    }
    #pragma unroll
    for (int mtp = 0; mtp < 4; ++mtp) {
      u32 p[8];
      #pragma unroll
      for (int j2 = 0; j2 < 8; ++j2)
        p[j2] = packf16(fmaxf(acc[mtp][2 * j2], 0.0f), fmaxf(acc[mtp][2 * j2 + 1], 0.0f));
      #pragma unroll
      for (int u = 0; u < 2; ++u)
        #pragma unroll
        for (int w = 0; w < 2; ++w) {
          u32 va = p[w + 4 * u], vb = p[w + 4 * u + 2];
          asm("v_permlane32_swap_b32 %0, %1" : "+v"(va), "+v"(vb));
          Bf[2 * mtp + u][w]     = va;
          Bf[2 * mtp + u][w + 2] = vb;
        }
    }
  }

  f32x16 a4[2];
  #pragma unroll
  for (int mt4 = 0; mt4 < 2; ++mt4)
    #pragma unroll
    for (int r = 0; r < 16; ++r) a4[mt4][r] = 0.0f;
  #pragma unroll
  for (int s = 0; s < 8; ++s) {
    f16x8 B = bfrag(Bf[s]);
    #pragma unroll
    for (int mt4 = 0; mt4 < 2; ++mt4) {
      f16x8 A = *(const f16x8*)(w4f + (((size_t)(s * 2 + mt4) * 64 + ln) << 3));
      a4[mt4] = __builtin_amdgcn_mfma_f32_32x32x16_f16(A, B, a4[mt4], 0, 0, 0);
    }
  }

  float tacc[2][16];
  #pragma unroll
  for (int mt4 = 0; mt4 < 2; ++mt4)
    #pragma unroll
    for (int r = 0; r < 16; ++r) {
      float v = a4[mt4][r] * wgt;
      v += __shfl_xor(v, 1, 64);
      v += __shfl_xor(v, 2, 64);
      tacc[mt4][r] = v;
    }

  if (c == 0) {
    #pragma unroll
    for (int mt4 = 0; mt4 < 2; ++mt4)
      #pragma unroll
      for (int j = 0; j < 4; ++j) {
        int mo = (mt4 << 5) + (j << 3) + (h << 2);
        f32x4 bv = *(const f32x4*)(b4 + mo);
        f32x4 res;
        #pragma unroll
        for (int q = 0; q < 4; ++q) res[q] = tacc[mt4][4 * j + q] + bv[q];
        *(f32x4*)(out + (size_t)gq * 64 + mo) = res;
      }
  }
}

// ---------------------------------------------------------------------------
extern "C" void kernel_launch(void* const* d_in, const int* in_sizes, int n_in,
                              void* d_out, int out_size, void* d_ws, size_t ws_size,
                              hipStream_t stream)
{
  const float* x     = (const float*)d_in[0];
  const float* coord = (const float*)d_in[1];
  const float* cell  = (const float*)d_in[2];
  const float* w0    = (const float*)d_in[3];
  const float* b0    = (const float*)d_in[4];
  const float* w1    = (const float*)d_in[5];
  const float* b1    = (const float*)d_in[6];
  const float* w2    = (const float*)d_in[7];
  const float* b2    = (const float*)d_in[8];
  const float* w3    = (const float*)d_in[9];
  const float* b3    = (const float*)d_in[10];
  const float* w4    = (const float*)d_in[11];
  const float* b4    = (const float*)d_in[12];
  U16* ws = (U16*)d_ws;
  u32* diag = (u32*)(ws + DIAG_OFF);

  hipLaunchKernelGGL(k_prepw,  dim3(50),  dim3(256), 0, stream, w0, w1, w2, w3, w4, ws);
  hipLaunchKernelGGL(k_stage1, dim3(512), dim3(256), 0, stream,
                     x, ws + W0F_OFF, b0, ws + P_OFF);
  hipLaunchKernelGGL(s2_diagA, dim3(512), dim3(256), 0, stream,
                     ws + W1F_OFF, ws + W1F_OFF + 16384, ws + W1F_OFF + 32768, ws + W4F_OFF,
                     diag);
  hipLaunchKernelGGL(s2_diagB, dim3(512), dim3(256), 0, stream, diag + 131072);
  hipLaunchKernelGGL(s2_diagC, dim3(512), dim3(256), 0, stream,
                     ws + P_OFF, coord, cell, w0, diag + 262144);
  hipLaunchKernelGGL(k_stage2, dim3(512), dim3(256), 0, stream,
                     ws + P_OFF, coord, cell, w0,
                     ws + W1F_OFF, ws + W1F_OFF + 16384, ws + W1F_OFF + 32768, ws + W4F_OFF,
                     b1, b2, b3, b4, (float*)d_out);
}

// Round 14
// 53.435 us; speedup vs baseline: 4.1084x; 4.1084x over previous
//
#include <hip/hip_runtime.h>

// ---------------------------------------------------------------------------
// LIIF forward, MI355X (r14 = fused cooperative-block MLP).
//   k_prepw  : 34 blocks — weight repack to 16x16x32 frag layouts [r10 proven]
//   k_stage1 : fused transpose+conv -> P                          [r7/r10 proven]
//   k_stage2 : ONE kernel, 1024 blocks x 64 rows: h0 build -> LDS actT ->
//              3 in-place layer GEMMs (double-barriered, r1-proven pattern)
//              -> final GEMM + corner combine -> out. 4 blocks/CU, 4 w/SIMD.
// r13 ablation: monolithic stage2 = 37.5us; parts: loads 6 (L2-BW floor),
// compute 5.8, h0 4 -> 20us interaction loss, unfixable per r9/r11/r12.
// Cooperative structure amortizes weights per block and pipelines via TLP.
// ---------------------------------------------------------------------------

typedef unsigned short U16;
typedef unsigned int   u32;
using f16x8  = __attribute__((ext_vector_type(8)))  _Float16;
using f32x4  = __attribute__((ext_vector_type(4)))  float;
using u16x8  = __attribute__((ext_vector_type(8)))  U16;
using u16x4  = __attribute__((ext_vector_type(4)))  U16;

// ws layout (f16 element offsets) — r10 numbering (H region now unused)
#define P_OFF    8388608    // 2*16384*128 = 4,194,304
#define W0F_OFF  12582912   // 73,728  stage1 A-frags: [kpos][ks][mtile][lane][8]
#define W1G_OFF  12656640   // 3*16384 MLP A-frags:    [L][ks][mt][lane][8]
#define W4G_OFF  12705792   // 8,192   final A-frags:  [ks][mt4][lane][8]

__device__ __forceinline__ float h2f(U16 u){ _Float16 h; __builtin_memcpy(&h,&u,2); return (float)h; }
__device__ __forceinline__ U16 f2h(float f){ _Float16 h = (_Float16)f; U16 u; __builtin_memcpy(&u,&h,2); return u; }

__device__ __forceinline__ int nearest_idx(float g){
  float t = (g + 1.0f) * 128.0f;   // exact
  t = (t - 1.0f) * 0.5f;           // exact
  float r = rintf(t);              // half-even == np.round
  r = fminf(fmaxf(r, 0.0f), 127.0f);
  return (int)r;
}
__device__ __forceinline__ float seqv(int i){ return -0.9921875f + 0.015625f*(float)i; }

// corner: 0:(-1,-1) 1:(-1,+1) 2:(+1,-1) 3:(+1,+1)
__device__ __forceinline__ void corner_calc(float c0, float c1, int corner,
                                            int& iy, int& ix, float& rel0, float& rel1){
  const float rx = 0.0078125f;
  float sx = (corner & 2) ? rx : -rx;
  float sy = (corner & 1) ? rx : -rx;
  float a0 = c0 + sx; a0 = a0 + 1e-6f; a0 = fminf(fmaxf(a0, -1.0f + 1e-6f), 1.0f - 1e-6f);
  float a1 = c1 + sy; a1 = a1 + 1e-6f; a1 = fminf(fmaxf(a1, -1.0f + 1e-6f), 1.0f - 1e-6f);
  iy = nearest_idx(a0);
  ix = nearest_idx(a1);
  rel0 = (c0 - seqv(ix)) * 128.0f;   // ref quirk: rel0 uses seq[ix]
  rel1 = (c1 - seqv(iy)) * 128.0f;
}

// ---------------------------------------------------------------------------
// k_prepw: 34 blocks (verbatim r10, passing).
__global__ __launch_bounds__(256) void k_prepw(
    const float* __restrict__ w0, const float* __restrict__ w1,
    const float* __restrict__ w2, const float* __restrict__ w3,
    const float* __restrict__ w4, U16* __restrict__ ws)
{
  __shared__ U16 sh[64 * 72];
  const int tid = threadIdx.x, bid = blockIdx.x;

  if (bid < 12) {
    int L = bid >> 2, ks = bid & 3;
    const float* src = (L == 0) ? w1 : (L == 1) ? w2 : w3;
    {
      int kl = tid >> 3, m0 = (tid & 7) << 4;
      const float* p = src + (((ks << 5) + kl) << 7) + m0;
      #pragma unroll
      for (int j = 0; j < 4; ++j) {
        float4 v = *(const float4*)(p + (j << 2));
        U16* d = &sh[(kl << 7) + m0 + (j << 2)];
        d[0]=f2h(v.x); d[1]=f2h(v.y); d[2]=f2h(v.z); d[3]=f2h(v.w);
      }
    }
    __syncthreads();
    {
      int lane = tid & 63, mtb = tid >> 6;
      #pragma unroll
      for (int i = 0; i < 2; ++i) {
        int mt = mtb + (i << 2);
        u16x8 o;
        #pragma unroll
        for (int e = 0; e < 8; ++e)
          o[e] = sh[((((lane >> 4) << 3) + e) << 7) + (mt << 4) + (lane & 15)];
        *(u16x8*)(ws + W1G_OFF + (L << 14) + (((ks << 3) + mt) << 9) + (lane << 3)) = o;
      }
    }
  } else if (bid < 16) {
    int ks = bid - 12;
    {
      int kl = tid >> 3, m0 = (tid & 7) << 3;
      const float* p = w4 + (((ks << 5) + kl) << 6) + m0;
      float4 a = *(const float4*)p, b2 = *(const float4*)(p + 4);
      U16* d = &sh[(kl << 6) + m0];
      d[0]=f2h(a.x); d[1]=f2h(a.y); d[2]=f2h(a.z); d[3]=f2h(a.w);
      d[4]=f2h(b2.x); d[5]=f2h(b2.y); d[6]=f2h(b2.z); d[7]=f2h(b2.w);
    }
    __syncthreads();
    {
      int lane = tid & 63, mt4 = tid >> 6;
      u16x8 o;
      #pragma unroll
      for (int e = 0; e < 8; ++e)
        o[e] = sh[((((lane >> 4) << 3) + e) << 6) + (mt4 << 4) + (lane & 15)];
      *(u16x8*)(ws + W4G_OFF + (((ks << 2) + mt4) << 9) + (lane << 3)) = o;
    }
  } else {
    int t2 = bid - 16, kpos = t2 >> 1, ks = t2 & 1;
    {
      int cc = tid >> 3, o0 = (tid & 7) << 4;
      const float* p = w0 + ((size_t)((((ks << 5) + cc) * 9) + kpos) << 7) + o0;
      #pragma unroll
      for (int j = 0; j < 4; ++j) {
        float4 v = *(const float4*)(p + (j << 2));
        U16* d = &sh[(cc << 7) + o0 + (j << 2)];
        d[0]=f2h(v.x); d[1]=f2h(v.y); d[2]=f2h(v.z); d[3]=f2h(v.w);
      }
    }
    __syncthreads();
    {
      int lane = tid & 63, mt0 = tid >> 6;
      #pragma unroll
      for (int i = 0; i < 2; ++i) {
        int mtile = mt0 + (i << 2);
        u16x8 o;
        #pragma unroll
        for (int e = 0; e < 8; ++e)
          o[e] = sh[((((lane >> 4) << 3) + e) << 7) + (mtile << 4) + (lane & 15)];
        *(u16x8*)(ws + W0F_OFF + (((((kpos << 1) + ks) << 3) + mtile) << 9) + (lane << 3)) = o;
      }
    }
  }
}

// ---------------------------------------------------------------------------
// Stage 1 (fused transpose+conv): verbatim r7/r10 (passing).
__global__ __launch_bounds__(256) void k_stage1(const float* __restrict__ x,
                                                const U16* __restrict__ w0f,
                                                const float* __restrict__ b0,
                                                U16* __restrict__ P)
{
  __shared__ U16 araw[3 * 66 * 64];
  const int tid = threadIdx.x, bid = blockIdx.x;
  const int b = bid >> 8, rem = bid & 255;
  const int y = rem >> 1, x0 = (rem & 1) << 6;

  {
    int c = tid & 63, dy = tid >> 6;
    if (dy < 3) {
      int yy = y + dy - 1;
      bool rowok = (yy >= 0) && (yy < 128);
      const float* xr = rowok
        ? (x + ((((size_t)b << 6) + c) << 14) + ((size_t)yy << 7)) : x;
      U16* arow = &araw[(dy * 66) * 64];
      {
        float v0 = 0.0f, v65 = 0.0f;
        if (rowok && x0 > 0)        v0  = xr[x0 - 1];
        if (rowok && x0 + 64 < 128) v65 = xr[x0 + 64];
        arow[0 * 64 + c] = f2h(v0);
        arow[65 * 64 + (c ^ 8)] = f2h(v65);
      }
      if (rowok) {
        #pragma unroll
        for (int g = 0; g < 16; ++g) {
          float4 v = *(const float4*)(xr + x0 + (g << 2));
          #pragma unroll
          for (int j = 0; j < 4; ++j) {
            int xp = 1 + (g << 2) + j;
            float vj = (j == 0) ? v.x : (j == 1) ? v.y : (j == 2) ? v.z : v.w;
            arow[xp * 64 + (c ^ ((xp & 7) << 3))] = f2h(vj);
          }
        }
      } else {
        #pragma unroll
        for (int xp = 1; xp <= 64; ++xp)
          arow[xp * 64 + (c ^ ((xp & 7) << 3))] = f2h(0.0f);
      }
    }
  }
  __syncthreads();

  const int wv = tid >> 6, ln = tid & 63;
  const int lrow = ln & 15, lg = ln >> 4;

  f32x4 acc[2][4];
  #pragma unroll
  for (int m = 0; m < 2; ++m)
    #pragma unroll
    for (int n = 0; n < 4; ++n) acc[m][n] = (f32x4){0.f, 0.f, 0.f, 0.f};

  #pragma unroll
  for (int kpos = 0; kpos < 9; ++kpos) {
    const int dyr = kpos / 3;
    const int dx = kpos % 3 - 1;
    f16x8 a[2][2];
    #pragma unroll
    for (int mf = 0; mf < 2; ++mf)
      #pragma unroll
      for (int ks = 0; ks < 2; ++ks) {
        size_t off = ((size_t)((((kpos << 1) + ks) << 3) + ((wv << 1) + mf)) << 9) + (ln << 3);
        a[mf][ks] = *(const f16x8*)(w0f + off);
      }
    #pragma unroll
    for (int ks = 0; ks < 2; ++ks)
      #pragma unroll
      for (int nf = 0; nf < 4; ++nf) {
        int xp = (nf << 4) + lrow + dx + 1;
        int cc = ((ks << 5) + (lg << 3)) ^ ((xp & 7) << 3);
        f16x8 bf = *(const f16x8*)(&araw[(dyr * 66 + xp) * 64 + cc]);
        acc[0][nf] = __builtin_amdgcn_mfma_f32_16x16x32_f16(a[0][ks], bf, acc[0][nf], 0, 0, 0);
        acc[1][nf] = __builtin_amdgcn_mfma_f32_16x16x32_f16(a[1][ks], bf, acc[1][nf], 0, 0, 0);
      }
  }

  #pragma unroll
  for (int mf = 0; mf < 2; ++mf) {
    int o0 = (wv << 5) + (mf << 4) + (lg << 2);
    float bb[4];
    #pragma unroll
    for (int r = 0; r < 4; ++r) bb[r] = b0[o0 + r];
    #pragma unroll
    for (int nf = 0; nf < 4; ++nf) {
      int px = x0 + (nf << 4) + lrow;
      u16x4 w;
      #pragma unroll
      for (int r = 0; r < 4; ++r) w[r] = f2h(acc[mf][nf][r] + bb[r]);
      *(u16x4*)(P + ((size_t)((b << 14) + (y << 7) + px)) * 128 + o0) = w;
    }
  }
}

// ---------------------------------------------------------------------------
// Stage 2 fused: 1024 blocks x 64 rows (row = gq*4 + corner).
// actT swizzled [r][k ^ ((r&7)<<3)], persistent across layers.
__global__ __launch_bounds__(256) void k_stage2(
    const U16* __restrict__ P,
    const float* __restrict__ coord, const float* __restrict__ cell,
    const float* __restrict__ w0,
    const U16* __restrict__ w1g, const U16* __restrict__ w2g,
    const U16* __restrict__ w3g, const U16* __restrict__ w4g,
    const float* __restrict__ b1, const float* __restrict__ b2,
    const float* __restrict__ b3, const float* __restrict__ b4,
    float* __restrict__ out)
{
  __shared__ U16 actT[64 * 128];   // 16 KB
  const int tid = threadIdx.x, bid = blockIdx.x;
  const int r0 = bid << 6;

  // ---- h0 build (r10 mlp0 body, 64-row reshape: r=tid>>2, 4 col-quarters) ----
  {
    int r = tid >> 2, hf = tid & 3;
    int rr = r0 + r;
    int gq = rr >> 2, cc = rr & 3, bimg = gq >> 13;
    float c0v = coord[gq * 2 + 0], c1v = coord[gq * 2 + 1];
    float rc0 = cell[gq * 2 + 0] * 128.0f, rc1 = cell[gq * 2 + 1] * 128.0f;
    int iy, ix; float rel0, rel1;
    corner_calc(c0v, c1v, cc, iy, ix, rel0, rel1);
    int lin = iy * 128 + ix;
    const U16* Pr = P + (((size_t)(bimg << 14) + lin) << 7);
    const float* tu = w0 + 576 * 128;
    const float* tv = tu + 128;
    const float* ts2 = tv + 128;
    const float* tt = ts2 + 128;
    #pragma unroll
    for (int j = 0; j < 4; ++j) {
      int n0 = (hf << 5) + (j << 3);
      u16x8 pv = *(const u16x8*)(Pr + n0);
      f32x4 ua = *(const f32x4*)(tu + n0),  ub = *(const f32x4*)(tu + n0 + 4);
      f32x4 va = *(const f32x4*)(tv + n0),  vb = *(const f32x4*)(tv + n0 + 4);
      f32x4 sa = *(const f32x4*)(ts2 + n0), sb = *(const f32x4*)(ts2 + n0 + 4);
      f32x4 ta = *(const f32x4*)(tt + n0),  tb = *(const f32x4*)(tt + n0 + 4);
      u16x8 res;
      #pragma unroll
      for (int e = 0; e < 8; ++e) {
        float uu  = (e < 4) ? ua[e & 3] : ub[e & 3];
        float vvv = (e < 4) ? va[e & 3] : vb[e & 3];
        float ss  = (e < 4) ? sa[e & 3] : sb[e & 3];
        float t2  = (e < 4) ? ta[e & 3] : tb[e & 3];
        float hh = h2f(pv[e]) + rel0 * uu + rel1 * vvv + rc0 * ss + rc1 * t2;
        res[e] = f2h(fmaxf(hh, 0.0f));
      }
      *(u16x8*)(&actT[(r << 7) + (n0 ^ ((r & 7) << 3))]) = res;
    }
  }
  __syncthreads();

  const int wv = tid >> 6, ln = tid & 63;
  const int lrow = ln & 15, lg = ln >> 4;

  // ---- hidden layers 1..3: GEMM from actT, in-place write (r1 pattern) ----
  #pragma unroll
  for (int L = 0; L < 3; ++L) {
    const U16* wg = (L == 0) ? w1g : (L == 1) ? w2g : w3g;
    const float* bL = (L == 0) ? b1 : (L == 1) ? b2 : b3;
    f32x4 acc[2][4];
    #pragma unroll
    for (int mt = 0; mt < 2; ++mt) {
      int o0 = (((wv << 1) + mt) << 4) + (lg << 2);
      f32x4 bv = *(const f32x4*)(bL + o0);
      #pragma unroll
      for (int nf = 0; nf < 4; ++nf) acc[mt][nf] = bv;
    }
    #pragma unroll
    for (int ks = 0; ks < 4; ++ks) {
      f16x8 a[2];
      #pragma unroll
      for (int mt = 0; mt < 2; ++mt)
        a[mt] = *(const f16x8*)(wg + (((ks << 3) + (wv << 1) + mt) << 9) + (ln << 3));
      #pragma unroll
      for (int nf = 0; nf < 4; ++nf) {
        int rr = (nf << 4) + lrow;
        int kk = ((ks << 5) + (lg << 3)) ^ ((rr & 7) << 3);
        f16x8 bf = *(const f16x8*)(&actT[(rr << 7) + kk]);
        acc[0][nf] = __builtin_amdgcn_mfma_f32_16x16x32_f16(a[0], bf, acc[0][nf], 0, 0, 0);
        acc[1][nf] = __builtin_amdgcn_mfma_f32_16x16x32_f16(a[1], bf, acc[1][nf], 0, 0, 0);
      }
    }
    __syncthreads();   // all reads of actT done
    #pragma unroll
    for (int mt = 0; mt < 2; ++mt) {
      int o0 = (((wv << 1) + mt) << 4) + (lg << 2);
      #pragma unroll
      for (int nf = 0; nf < 4; ++nf) {
        int rr = (nf << 4) + lrow;
        u16x4 w;
        #pragma unroll
        for (int r = 0; r < 4; ++r) w[r] = f2h(fmaxf(acc[mt][nf][r], 0.0f));
        *(u16x4*)(&actT[(rr << 7) + (o0 ^ ((rr & 7) << 3))]) = w;
      }
    }
    __syncthreads();   // writes visible for next layer
  }

  // ---- final layer 128 -> 64 + corner combine (r10 mlp4 body, 1 nfl) ----
  f32x4 acc4[4];
  #pragma unroll
  for (int mt4 = 0; mt4 < 4; ++mt4) acc4[mt4] = (f32x4){0.f, 0.f, 0.f, 0.f};
  #pragma unroll
  for (int ks = 0; ks < 4; ++ks) {
    f16x8 a[4];
    #pragma unroll
    for (int mt4 = 0; mt4 < 4; ++mt4)
      a[mt4] = *(const f16x8*)(w4g + (((ks << 2) + mt4) << 9) + (ln << 3));
    int rr = (wv << 4) + lrow;
    int kk = ((ks << 5) + (lg << 3)) ^ ((rr & 7) << 3);
    f16x8 bf = *(const f16x8*)(&actT[(rr << 7) + kk]);
    #pragma unroll
    for (int mt4 = 0; mt4 < 4; ++mt4)
      acc4[mt4] = __builtin_amdgcn_mfma_f32_16x16x32_f16(a[mt4], bf, acc4[mt4], 0, 0, 0);
  }

  {
    int rl = (wv << 4) + lrow;
    int rglob = r0 + rl;
    int gq = rglob >> 2, cc = rl & 3;
    float c0v = coord[gq * 2 + 0], c1v = coord[gq * 2 + 1];
    float area[4];
    #pragma unroll
    for (int c4 = 0; c4 < 4; ++c4) {
      int iy, ix; float rr0, rr1;
      corner_calc(c0v, c1v, c4, iy, ix, rr0, rr1);
      area[c4] = fabsf(rr0 * rr1) + 1e-9f;
    }
    float tot = ((area[0] + area[1]) + area[2]) + area[3];
    float wgt = area[3 - cc] / tot;        // perm = (3,2,1,0)
    float tacc[4][4];
    #pragma unroll
    for (int mt4 = 0; mt4 < 4; ++mt4)
      #pragma unroll
      for (int r = 0; r < 4; ++r) {
        float v = acc4[mt4][r] * wgt;
        v += __shfl_xor(v, 1, 64);
        v += __shfl_xor(v, 2, 64);
        tacc[mt4][r] = v;
      }
    if (cc == 0) {
      #pragma unroll
      for (int mt4 = 0; mt4 < 4; ++mt4) {
        int mo = (mt4 << 4) + (lg << 2);
        f32x4 bv = *(const f32x4*)(b4 + mo);
        f32x4 res;
        #pragma unroll
        for (int r = 0; r < 4; ++r) res[r] = tacc[mt4][r] + bv[r];
        *(f32x4*)(out + (size_t)gq * 64 + mo) = res;
      }
    }
  }
}

// ---------------------------------------------------------------------------
extern "C" void kernel_launch(void* const* d_in, const int* in_sizes, int n_in,
                              void* d_out, int out_size, void* d_ws, size_t ws_size,
                              hipStream_t stream)
{
  const float* x     = (const float*)d_in[0];
  const float* coord = (const float*)d_in[1];
  const float* cell  = (const float*)d_in[2];
  const float* w0    = (const float*)d_in[3];
  const float* b0    = (const float*)d_in[4];
  const float* w1    = (const float*)d_in[5];
  const float* b1    = (const float*)d_in[6];
  const float* w2    = (const float*)d_in[7];
  const float* b2    = (const float*)d_in[8];
  const float* w3    = (const float*)d_in[9];
  const float* b3    = (const float*)d_in[10];
  const float* w4    = (const float*)d_in[11];
  const float* b4    = (const float*)d_in[12];
  U16* ws = (U16*)d_ws;

  hipLaunchKernelGGL(k_prepw,  dim3(34),   dim3(256), 0, stream, w0, w1, w2, w3, w4, ws);
  hipLaunchKernelGGL(k_stage1, dim3(512),  dim3(256), 0, stream,
                     x, ws + W0F_OFF, b0, ws + P_OFF);
  hipLaunchKernelGGL(k_stage2, dim3(1024), dim3(256), 0, stream,
                     ws + P_OFF, coord, cell, w0,
                     ws + W1G_OFF, ws + W1G_OFF + 16384, ws + W1G_OFF + 32768, ws + W4G_OFF,
                     b1, b2, b3, b4, (float*)d_out);
}